// Round 10
// baseline (2895.578 us; speedup 1.0000x reference)
//
#include <hip/hip_runtime.h>

typedef _Float16 h8 __attribute__((ext_vector_type(8)));
typedef float v4f __attribute__((ext_vector_type(4)));
typedef unsigned long long u64;

#define B_  256
#define T_  512
#define I_  64
#define H_  512

// workspace layout (bytes)
#define OFF_W16   0                                   // [2048][512] f16
#define OFF_WIH   (OFF_W16 + 2048*512*2)              // [2048][64]  f16
#define OFF_BIAS  (OFF_WIH + 2048*64*2)               // [2048]      f32 (b_ih+b_hh)
#define OFF_X16   (OFF_BIAS + 2048*4)                 // [512][256][64] f16 (t-major)
#define OFF_H0    (OFF_X16 + 512*256*64*2)            // [256][512] f16
#define OFF_H1    (OFF_H0 + 256*512*2)                // [256][512] f16
#define OFF_CTR   (OFF_H1 + 256*512*2)                // 16 counters, 64B apart

__device__ __forceinline__ float sigf(float x) {
    float e = __builtin_amdgcn_exp2f(-1.442695041f * x);
    return __builtin_amdgcn_rcpf(1.f + e);
}
__device__ __forceinline__ float tanhf_(float x) {
    float e = __builtin_amdgcn_exp2f(2.885390082f * x);  // exp(2x)
    return 1.f - 2.f * __builtin_amdgcn_rcpf(e + 1.f);
}

union Pack4 { _Float16 f[4]; u64 u; };
union HU    { u64 u[2]; h8 v; };

__global__ void prep_w(const float* __restrict__ Wih, const float* __restrict__ Whh,
                       const float* __restrict__ bih, const float* __restrict__ bhh,
                       _Float16* __restrict__ W16, _Float16* __restrict__ Wih16,
                       float* __restrict__ bias, _Float16* __restrict__ h0,
                       unsigned* __restrict__ ctr) {
    int idx = blockIdx.x * 256 + threadIdx.x;          // grid covers 2048*512
    W16[idx] = (_Float16)Whh[idx];
    if (idx < 2048 * 64)  Wih16[idx] = (_Float16)Wih[idx];
    if (idx < 2048)       bias[idx] = bih[idx] + bhh[idx];
    // h0 zeros must be visible at the IF$ coherence point (lstm_k reads them
    // with device-scope loads that bypass L2) -> device-scope atomic stores.
    if (idx < 32768)
        __hip_atomic_store((u64*)h0 + idx, 0ull,
                           __ATOMIC_RELAXED, __HIP_MEMORY_SCOPE_AGENT);
    if (idx < 256)
        __hip_atomic_store(ctr + idx, 0u, __ATOMIC_RELAXED, __HIP_MEMORY_SCOPE_AGENT);
}

__global__ void prep_x(const float* __restrict__ x, _Float16* __restrict__ x16) {
    int idx = blockIdx.x * 256 + threadIdx.x;          // grid covers 512*256*64
    int t = idx >> 14;                                  // / (256*64)
    int rem = idx & 16383;
    int b = rem >> 6;
    int i = rem & 63;
    x16[idx] = (_Float16)x[((size_t)b * T_ + t) * I_ + i];
}

// r9 structure (1306us steady, proven) minus the LDS stage:
// In the swapped formulation (A=W, B=h) all 4 waves consume the IDENTICAL
// B-fragment, and each lane's B-frag for chunk kk is a contiguous 16B slice
// h[B0+r][kk*32+q*8..+7] -> load it DIRECTLY from agent memory (r3's
// harness-proven address pattern). Deletes: 8 staging loads + LDS scatter +
// barrier b1 + 16 ds_read_b128 + all bank conflicts + stage-skew coupling.
// Cost: 4x h read traffic at the MALL (64KB/wg-step; h set is 32KB -> no HBM
// delta). Protocol EXACTLY r9 (counter RMW + tid0 poll + last-publisher skip).
__launch_bounds__(256, 1)
__global__ void lstm_k(const _Float16* __restrict__ W16, const _Float16* __restrict__ Wih16,
                       const float* __restrict__ bias, const _Float16* __restrict__ x16,
                       _Float16* __restrict__ h0, _Float16* __restrict__ h1,
                       unsigned* __restrict__ ctr) {
    const int tid  = threadIdx.x;
    const int lane = tid & 63;
    const int wv   = tid >> 6;        // wave = h-col sub-block (0..3)
    const int bg   = blockIdx.x & 15; // batch group (16 rows)
    const int cg   = blockIdx.x >> 4; // column group 0..7
    const int B0   = bg * 16;
    const int J0   = cg * 64;         // h-column base
    const int r    = lane & 15;
    const int q    = lane >> 4;

    // --- hoist weights as A-frags: 4 gates x 16 h-chunks + 2 x-chunks ---
    h8 afrag[4][16];
    h8 xafrag[4][2];
    float biasv[4][4];
#pragma unroll
    for (int g = 0; g < 4; ++g) {
        const int wrow = g * H_ + J0 + wv * 16 + r;     // gate-col index (A row)
#pragma unroll
        for (int kk = 0; kk < 16; ++kk)
            afrag[g][kk] = *(const h8*)(W16 + (size_t)wrow * H_ + kk * 32 + q * 8);
#pragma unroll
        for (int c = 0; c < 2; ++c)
            xafrag[g][c] = *(const h8*)(Wih16 + (size_t)wrow * I_ + c * 32 + q * 8);
        // D rows (M=gate-col) = q*4+reg -> bias per (g, reg)
#pragma unroll
        for (int reg = 0; reg < 4; ++reg)
            biasv[g][reg] = bias[g * H_ + J0 + wv * 16 + q * 4 + reg];
    }

    // cell state: lane owns batch row B0+r, h-cols J0+wv*16+q*4+{0..3}
    float cc[4] = {0.f, 0.f, 0.f, 0.f};

    unsigned* myctr = ctr + bg * 16;  // 64B-separated per-bg counters

    // x B-frags for step 0: lane (r,q) needs x16[t][B0+r][c*32 + q*8 ..+7]
    const _Float16* xrow0 = x16 + (size_t)(B0 + r) * I_ + q * 8;
    h8 xa0 = *(const h8*)(xrow0);
    h8 xa1 = *(const h8*)(xrow0 + 32);

    for (int s = 0; s < T_; ++s) {
        const _Float16* hp = (s & 1) ? h1 : h0;
        _Float16*       hn = (s & 1) ? h0 : h1;

        // ---- B-frags (h) direct agent loads: row B0+r = 128 u64 units,
        //      chunk kk at u64 offset kk*8 + q*2 (r3-proven pattern) ----
        HU hb[16];
        {
            const u64* hr = (const u64*)hp + (size_t)(B0 + r) * 128 + q * 2;
#pragma unroll
            for (int kk = 0; kk < 16; ++kk) {
                hb[kk].u[0] = __hip_atomic_load(hr + kk * 8,
                                                __ATOMIC_RELAXED, __HIP_MEMORY_SCOPE_AGENT);
                hb[kk].u[1] = __hip_atomic_load(hr + kk * 8 + 1,
                                                __ATOMIC_RELAXED, __HIP_MEMORY_SCOPE_AGENT);
            }
        }

        // ---- x-part MFMAs overlap the h-load latency (register-only) ----
        v4f a0 = {0,0,0,0}, a1 = {0,0,0,0}, a2 = {0,0,0,0}, a3 = {0,0,0,0};
        a0 = __builtin_amdgcn_mfma_f32_16x16x32_f16(xafrag[0][0], xa0, a0, 0, 0, 0);
        a1 = __builtin_amdgcn_mfma_f32_16x16x32_f16(xafrag[1][0], xa0, a1, 0, 0, 0);
        a2 = __builtin_amdgcn_mfma_f32_16x16x32_f16(xafrag[2][0], xa0, a2, 0, 0, 0);
        a3 = __builtin_amdgcn_mfma_f32_16x16x32_f16(xafrag[3][0], xa0, a3, 0, 0, 0);
        a0 = __builtin_amdgcn_mfma_f32_16x16x32_f16(xafrag[0][1], xa1, a0, 0, 0, 0);
        a1 = __builtin_amdgcn_mfma_f32_16x16x32_f16(xafrag[1][1], xa1, a1, 0, 0, 0);
        a2 = __builtin_amdgcn_mfma_f32_16x16x32_f16(xafrag[2][1], xa1, a2, 0, 0, 0);
        a3 = __builtin_amdgcn_mfma_f32_16x16x32_f16(xafrag[3][1], xa1, a3, 0, 0, 0);

        // ---- h-part MFMA: 16 chunks; B-frag feeds all 4 gates ----
        //      (compiler inserts per-chunk vmcnt -> loads pipeline into MFMAs)
#pragma unroll
        for (int kk = 0; kk < 16; ++kk) {
            a0 = __builtin_amdgcn_mfma_f32_16x16x32_f16(afrag[0][kk], hb[kk].v, a0, 0, 0, 0);
            a1 = __builtin_amdgcn_mfma_f32_16x16x32_f16(afrag[1][kk], hb[kk].v, a1, 0, 0, 0);
            a2 = __builtin_amdgcn_mfma_f32_16x16x32_f16(afrag[2][kk], hb[kk].v, a2, 0, 0, 0);
            a3 = __builtin_amdgcn_mfma_f32_16x16x32_f16(afrag[3][kk], hb[kk].v, a3, 0, 0, 0);
        }

        // ---- cell in registers; ONE packed 8B h' store per lane ----
        // C/D [m89]: col = lane&15 = batch r; row = q*4+reg = h-col offset
        {
            Pack4 pk;
#pragma unroll
            for (int reg = 0; reg < 4; ++reg) {
                float iv = sigf  (a0[reg] + biasv[0][reg]);
                float fv = sigf  (a1[reg] + biasv[1][reg]);
                float gv = tanhf_(a2[reg] + biasv[2][reg]);
                float ov = sigf  (a3[reg] + biasv[3][reg]);
                cc[reg] = fv * cc[reg] + iv * gv;
                pk.f[reg] = (_Float16)(ov * tanhf_(cc[reg]));
            }
            __hip_atomic_store(
                (u64*)(hn + (size_t)(B0 + r) * H_ + J0 + wv * 16 + q * 4),
                pk.u, __ATOMIC_RELAXED, __HIP_MEMORY_SCOPE_AGENT);
        }
        __syncthreads();   // implicit vmcnt(0): all waves' h' stores ack'd at IF$

        // ---- per-group barrier: counter RMW; last publisher skips the poll ----
        unsigned old = 0;
        const unsigned target = 8u * (unsigned)(s + 1);
        if (tid == 0)
            old = __hip_atomic_fetch_add(myctr, 1u,
                                         __ATOMIC_RELAXED, __HIP_MEMORY_SCOPE_AGENT);
        // x B-frag prefetch for s+1 overlaps the RMW/poll
        if (s + 1 < T_) {
            const _Float16* xr = x16 + ((size_t)(s + 1) * B_ + B0 + r) * I_ + q * 8;
            xa0 = *(const h8*)(xr);
            xa1 = *(const h8*)(xr + 32);
        }
        if (tid == 0 && old + 1 < target) {
            int guard = 0;
            while (__hip_atomic_load(myctr, __ATOMIC_RELAXED, __HIP_MEMORY_SCOPE_AGENT) < target) {
                __builtin_amdgcn_s_sleep(1);
                if (++guard > (1 << 17)) break;   // anti-hang: fail loud, not silent
            }
        }
        __syncthreads();
    }
}

__global__ void fc_k(const _Float16* __restrict__ hlast, const float* __restrict__ Wfc,
                     const float* __restrict__ bfc, float* __restrict__ out) {
    int b = blockIdx.x;
    int lane = threadIdx.x;   // 64 threads
    // h was written with device-scope stores (bypassing L2) -> read device-scope
    const u64* hp64 = (const u64*)(hlast + (size_t)b * H_);
    Pack4 p0, p1;
    p0.u = __hip_atomic_load(hp64 + lane * 2,     __ATOMIC_RELAXED, __HIP_MEMORY_SCOPE_AGENT);
    p1.u = __hip_atomic_load(hp64 + lane * 2 + 1, __ATOMIC_RELAXED, __HIP_MEMORY_SCOPE_AGENT);
    float sum = 0.f;
#pragma unroll
    for (int j = 0; j < 4; ++j) sum += (float)p0.f[j] * Wfc[lane * 8 + j];
#pragma unroll
    for (int j = 0; j < 4; ++j) sum += (float)p1.f[j] * Wfc[lane * 8 + 4 + j];
    for (int off = 32; off; off >>= 1) sum += __shfl_down(sum, off);
    if (lane == 0) out[b] = sum + bfc[0];
}

extern "C" void kernel_launch(void* const* d_in, const int* in_sizes, int n_in,
                              void* d_out, int out_size, void* d_ws, size_t ws_size,
                              hipStream_t stream) {
    (void)in_sizes; (void)n_in; (void)out_size; (void)ws_size;
    const float* x   = (const float*)d_in[0];
    const float* Wih = (const float*)d_in[1];
    const float* Whh = (const float*)d_in[2];
    const float* bih = (const float*)d_in[3];
    const float* bhh = (const float*)d_in[4];
    const float* Wfc = (const float*)d_in[5];
    const float* bfc = (const float*)d_in[6];
    float* out = (float*)d_out;

    char* ws = (char*)d_ws;
    _Float16* W16   = (_Float16*)(ws + OFF_W16);
    _Float16* Wih16 = (_Float16*)(ws + OFF_WIH);
    float*    biasf = (float*)(ws + OFF_BIAS);
    _Float16* x16   = (_Float16*)(ws + OFF_X16);
    _Float16* h0b   = (_Float16*)(ws + OFF_H0);
    _Float16* h1b   = (_Float16*)(ws + OFF_H1);
    unsigned* ctrb  = (unsigned*)(ws + OFF_CTR);

    hipLaunchKernelGGL(prep_w, dim3((2048 * 512) / 256), dim3(256), 0, stream,
                       Wih, Whh, bih, bhh, W16, Wih16, biasf, h0b, ctrb);
    hipLaunchKernelGGL(prep_x, dim3((512 * 256 * 64) / 256), dim3(256), 0, stream, x, x16);
    hipLaunchKernelGGL(lstm_k, dim3(128), dim3(256), 0, stream,
                       W16, Wih16, biasf, x16, h0b, h1b, ctrb);
    // T=512 even: last write went to buffer 0
    hipLaunchKernelGGL(fc_k, dim3(256), dim3(64), 0, stream, h0b, Wfc, bfc, out);
}